// Round 9
// baseline (395.874 us; speedup 1.0000x reference)
//
#include <hip/hip_runtime.h>
#include <hip/hip_bf16.h>

#define D_DIM 1024
#define N_EXP 16
#define TOPK  4
#define N_PAIR 4096
#define B_SZ  64
#define OUT_SZ 10
#define MAX_TILES 48

typedef __attribute__((ext_vector_type(8))) short short8_t;   // 8 bf16
typedef __attribute__((ext_vector_type(4))) float f32x4;

// ---------------- workspace layout (bytes); total ~100.1 MB (round-5 proven size) ----
static constexpr size_t WS_TKIDX   = 0;         // int[4096]
static constexpr size_t WS_TKGATE  = 16384;     // float[4096]
static constexpr size_t WS_OFFSETS = 32768;     // int[17]
static constexpr size_t WS_TE      = 33024;     // int[48]
static constexpr size_t WS_TRS     = 33280;     // int[48]
static constexpr size_t WS_NTILE   = 33536;     // int[1]
static constexpr size_t WS_PERMTOK = 33792;     // int[4096]
static constexpr size_t WS_PAIRROW = 50176;     // int[4096]
static constexpr size_t WS_XS      = 131072;    // short[1024*2048]  4 MB  [tok][kb][pl][32]
static constexpr size_t WS_HS      = 4325376;   // short[4096*2048] 16 MB  [row][kb][pl][32]
static constexpr size_t WS_OBUF    = 21102592;  // float[4096*1024] 16 MB
static constexpr size_t WS_WT      = 37879808;  // short[16*32*8*16*512] 64 MB (reused W1/W2)

// ---------------- fp32 -> bf16 split ----------------
__device__ __forceinline__ unsigned short f2bf_rn(float f) {
  unsigned int u = __float_as_uint(f);
  unsigned int r = (u + 0x7fffu + ((u >> 16) & 1u)) >> 16;
  return (unsigned short)r;
}
__device__ __forceinline__ void splitf(float f, short& h, short& l) {
  unsigned short hu = f2bf_rn(f);
  float fh = __uint_as_float(((unsigned int)hu) << 16);
  unsigned short lu = f2bf_rn(f - fh);
  h = (short)hu; l = (short)lu;
}

// ---------------- split_w job: one 32k x 128n tile of one expert ----------------
// WT layout: [e][kb(32)][cb(8)][n8(8)][pl(2)][lane(64)][8 shorts]
// B-frag semantics: lane l -> col = cb*128 + n8*16 + (l&15), k = kb*32 + (l>>4)*8 + i
__device__ void split_job(const float* __restrict__ W, short* __restrict__ WT, int j) {
  __shared__ float tb[32][132];
  const int e = j >> 8, kb = (j >> 3) & 31, cb = j & 7;
  const int t = threadIdx.x;
  const float* src = W + ((size_t)e << 20) + (size_t)(kb * 32) * 1024 + cb * 128;
  {
    const int rk = t >> 3, rc = (t & 7) * 16;
    #pragma unroll
    for (int q = 0; q < 4; q++)
      *(float4*)&tb[rk][rc + q*4] = *(const float4*)(src + (size_t)rk * 1024 + rc + q*4);
  }
  __syncthreads();
  short* dst = WT + (((size_t)e * 32 + kb) * 8 + cb) * 8192;
  #pragma unroll
  for (int q = 0; q < 2; q++) {
    int ent = t + 256 * q;            // 0..511 = n8(8) x lane(64)
    int n = ent >> 6, l = ent & 63;
    int l16 = l & 15, l4 = l >> 4;
    short8_t hv, lv;
    #pragma unroll
    for (int i = 0; i < 8; i++) {
      short hs, ls; splitf(tb[l4*8 + i][n*16 + l16], hs, ls);
      hv[i] = hs; lv[i] = ls;
    }
    *(short8_t*)(dst + (n*2 + 0) * 512 + l*8) = hv;
    *(short8_t*)(dst + (n*2 + 1) * 512 + l*8) = lv;
  }
}

// ---------------- standalone split kernel (W2 pass) ----------------
__global__ __launch_bounds__(256) void split_w_kernel(
    const float* __restrict__ W, short* __restrict__ WT) {
  split_job(W, WT, blockIdx.x);
}

// ---------------- prep: blocks [0,4096) split W1; [4096,4352) gate + split-x ----------------
__global__ __launch_bounds__(256) void prep_kernel(
    const float* __restrict__ x, const float* __restrict__ wg,
    const float* __restrict__ W1, short* __restrict__ WT,
    int* __restrict__ tk_idx, float* __restrict__ tk_gates,
    short* __restrict__ xs)
{
  const int bid = blockIdx.x;
  if (bid < 4096) { split_job(W1, WT, bid); return; }

  // ---- gate: one wave per token (round-5 proven) ----
  const int wave = threadIdx.x >> 6, lane = threadIdx.x & 63;
  const int n = (bid - 4096) * 4 + wave;
  const float* xr = x + (size_t)n * D_DIM + lane * 16;
  float xv[16];
  #pragma unroll
  for (int q = 0; q < 4; q++) {
    float4 v = *(const float4*)(xr + q*4);
    xv[q*4+0] = v.x; xv[q*4+1] = v.y; xv[q*4+2] = v.z; xv[q*4+3] = v.w;
  }
  {  // emit split x: lane covers k = lane*16..+15 -> kb = lane>>1, k_off = (lane&1)*16 + i
    short h[16], l[16];
    #pragma unroll
    for (int i = 0; i < 16; i++) splitf(xv[i], h[i], l[i]);
    short* base = xs + (size_t)n * 2048 + (lane >> 1) * 64 + (lane & 1) * 16;
    *(short8_t*)(base)          = *(short8_t*)&h[0];
    *(short8_t*)(base + 8)      = *(short8_t*)&h[8];
    *(short8_t*)(base + 32)     = *(short8_t*)&l[0];
    *(short8_t*)(base + 32 + 8) = *(short8_t*)&l[8];
  }
  float lg[N_EXP];
  #pragma unroll
  for (int e = 0; e < N_EXP; e++) lg[e] = 0.f;
  #pragma unroll
  for (int i = 0; i < 16; i++) {
    float xvi = xv[i];
    const float4* wrow = (const float4*)(wg + (size_t)(lane * 16 + i) * N_EXP);
    float4 w0 = wrow[0], w1 = wrow[1], w2 = wrow[2], w3 = wrow[3];
    lg[0]  = fmaf(xvi, w0.x, lg[0]);  lg[1]  = fmaf(xvi, w0.y, lg[1]);
    lg[2]  = fmaf(xvi, w0.z, lg[2]);  lg[3]  = fmaf(xvi, w0.w, lg[3]);
    lg[4]  = fmaf(xvi, w1.x, lg[4]);  lg[5]  = fmaf(xvi, w1.y, lg[5]);
    lg[6]  = fmaf(xvi, w1.z, lg[6]);  lg[7]  = fmaf(xvi, w1.w, lg[7]);
    lg[8]  = fmaf(xvi, w2.x, lg[8]);  lg[9]  = fmaf(xvi, w2.y, lg[9]);
    lg[10] = fmaf(xvi, w2.z, lg[10]); lg[11] = fmaf(xvi, w2.w, lg[11]);
    lg[12] = fmaf(xvi, w3.x, lg[12]); lg[13] = fmaf(xvi, w3.y, lg[13]);
    lg[14] = fmaf(xvi, w3.z, lg[14]); lg[15] = fmaf(xvi, w3.w, lg[15]);
  }
  #pragma unroll
  for (int e = 0; e < N_EXP; e++) {
    float s = lg[e];
    #pragma unroll
    for (int off = 32; off; off >>= 1) s += __shfl_xor(s, off);
    lg[e] = s;
  }
  float tv[TOPK]; int ti_[TOPK];
  #pragma unroll
  for (int k = 0; k < TOPK; k++) {
    float mv = -3.4e38f; int mi = 0;
    #pragma unroll
    for (int e = 0; e < N_EXP; e++) if (lg[e] > mv) { mv = lg[e]; mi = e; }
    tv[k] = mv; ti_[k] = mi; lg[mi] = -3.4e38f;
  }
  float mx = tv[0], ssum = 0.f, ex[TOPK];
  #pragma unroll
  for (int k = 0; k < TOPK; k++) { ex[k] = expf(tv[k] - mx); ssum += ex[k]; }
  float inv = 1.f / ssum;
  if (lane < TOPK) {
    tk_idx  [n*TOPK + lane] = ti_[lane];
    tk_gates[n*TOPK + lane] = ex[lane] * inv;
  }
}

// ---------------- scan + loss + scatter + tile table (round-5 proven) ----------------
__global__ __launch_bounds__(1024) void scan_scatter_kernel(
    const int* __restrict__ tk_idx, const float* __restrict__ tk_gates,
    int* __restrict__ offsets, int* __restrict__ perm_tok, int* __restrict__ pair_row,
    int* __restrict__ te, int* __restrict__ trs, int* __restrict__ ntile,
    float* __restrict__ out)
{
  __shared__ int cnt[N_EXP];
  __shared__ float fimp[N_EXP];
  __shared__ int cur[N_EXP];
  const int tid = threadIdx.x;
  if (tid < N_EXP) { cnt[tid] = 0; fimp[tid] = 0.f; }
  __syncthreads();
  #pragma unroll
  for (int pp = 0; pp < N_PAIR; pp += 1024) {
    int p = pp + tid;
    atomicAdd(&cnt[tk_idx[p]], 1);
    atomicAdd(&fimp[tk_idx[p]], tk_gates[p]);
  }
  __syncthreads();
  if (tid == 0) {
    int off = 0;
    for (int e = 0; e < N_EXP; e++) { offsets[e] = off; cur[e] = off; off += cnt[e]; }
    offsets[N_EXP] = off;
    float mi = 0.f, ml = 0.f;
    for (int e = 0; e < N_EXP; e++) { mi += fimp[e]; ml += (float)cnt[e]; }
    mi *= (1.f/N_EXP); ml *= (1.f/N_EXP);
    float vi = 0.f, vl = 0.f;
    for (int e = 0; e < N_EXP; e++) {
      float di = fimp[e] - mi;          vi += di*di;
      float dl = (float)cnt[e] - ml;    vl += dl*dl;
    }
    vi *= (1.f/(N_EXP-1)); vl *= (1.f/(N_EXP-1));   // ddof=1
    out[640] = 0.01f * (vi/(mi*mi + 1e-10f) + vl/(ml*ml + 1e-10f));
    out[641] = 0.f;   // MSE accumulator
    int T = 0;
    for (int e = 0; e < N_EXP; e++) {
      int nt = (cnt[e] + 127) >> 7;
      for (int s = 0; s < nt; s++) { te[T] = e; trs[T] = offsets[e] + s*128; T++; }
    }
    *ntile = T;
  }
  __syncthreads();
  #pragma unroll
  for (int pp = 0; pp < N_PAIR; pp += 1024) {
    int p = pp + tid;
    int row = atomicAdd(&cur[tk_idx[p]], 1);
    perm_tok[row] = p >> 2;
    pair_row[p] = row;
  }
}

// ---------------- grouped split-bf16 MFMA GEMM (A global->reg, B via LDS) ----------------
// tile 128x128, BK=32, 4 waves (2x2), 4x4 frags of 16x16x32/wave, 3-product split.
// A reads: 64 lanes cover 16 rows x 64 contiguous B -> full-line coalesced, no LDS.
// B: lane-linear b128 stage (conflict-free), double-buffered; raw s_barrier +
// lgkmcnt(0) only -> global prefetch stays in flight across barriers (T4).
// NOTE: launch_bounds(256,2) -> VGPR cap 256 (per-SIMD pool 512); ~170 live regs fit.
template<int IS_G1>
__global__ __launch_bounds__(256, 2) void ffn_gemm(
    const short* __restrict__ Asrc, const short* __restrict__ WTb,
    const float* __restrict__ bias,
    float* __restrict__ OutF, short* __restrict__ OutS,
    const int* __restrict__ offsets, const int* __restrict__ te,
    const int* __restrict__ trs, const int* __restrict__ ntile,
    const int* __restrict__ perm_tok)
{
  __shared__ short ldsB[2][8192];   // 32 KB
  const int job = blockIdx.x;
  const int ti = job >> 3, cb = job & 7;
  if (ti >= *ntile) return;
  const int e = te[ti];
  const int row_start = trs[ti];
  const int rows_here = min(128, offsets[e+1] - row_start);
  const int tid = threadIdx.x;
  const int lane = tid & 63, wid = tid >> 6;
  const int wr = wid >> 1, wc = wid & 1;
  const int l16 = lane & 15, l4 = lane >> 4;

  // per-lane A row bases (A-frag: lane holds row=l16, k = l4*8 + i)
  const short* abase[4];
  #pragma unroll
  for (int m = 0; m < 4; m++) {
    int r = min(row_start + wr*64 + m*16 + l16, N_PAIR - 1);
    size_t ar = IS_G1 ? (size_t)perm_tok[r] : (size_t)r;
    abase[m] = Asrc + ar * 2048 + l4 * 8;
  }
  const short* wjb = WTb + ((size_t)e * 256 + cb) * 8192;   // + kb*65536
  const int sg = (wid * 4) * 512 + lane * 8;                // stage offset (shorts)

  f32x4 acc[4][4];
  #pragma unroll
  for (int i = 0; i < 4; i++)
    #pragma unroll
    for (int jj = 0; jj < 4; jj++) acc[i][jj] = (f32x4)(0.f);

  short8_t AH0[4], AL0[4], AH1[4], AL1[4], rBa[4], rBb[4];

  // prologue: kb0+kb1 loads; stage kb0 -> buf0
  #pragma unroll
  for (int q = 0; q < 4; q++) rBa[q] = *(const short8_t*)(wjb + sg + q*512);
  #pragma unroll
  for (int q = 0; q < 4; q++) rBb[q] = *(const short8_t*)(wjb + 65536 + sg + q*512);
  #pragma unroll
  for (int m = 0; m < 4; m++) {
    AH0[m] = *(const short8_t*)(abase[m]);
    AL0[m] = *(const short8_t*)(abase[m] + 32);
    AH1[m] = *(const short8_t*)(abase[m] + 64);
    AL1[m] = *(const short8_t*)(abase[m] + 96);
  }
  #pragma unroll
  for (int q = 0; q < 4; q++) *(short8_t*)&ldsB[0][sg + q*512] = rBa[q];
  asm volatile("s_waitcnt lgkmcnt(0)" ::: "memory");
  __builtin_amdgcn_s_barrier();

  #define DO_MFMA48(AH, AL, BH, BL)                                                    \
    { _Pragma("unroll")                                                                \
      for (int n = 0; n < 4; n++) { _Pragma("unroll")                                  \
        for (int m = 0; m < 4; m++)                                                    \
          acc[m][n] = __builtin_amdgcn_mfma_f32_16x16x32_bf16(AH[m], BH[n], acc[m][n], 0,0,0); } \
      _Pragma("unroll")                                                                \
      for (int n = 0; n < 4; n++) { _Pragma("unroll")                                  \
        for (int m = 0; m < 4; m++)                                                    \
          acc[m][n] = __builtin_amdgcn_mfma_f32_16x16x32_bf16(AH[m], BL[n], acc[m][n], 0,0,0); } \
      _Pragma("unroll")                                                                \
      for (int n = 0; n < 4; n++) { _Pragma("unroll")                                  \
        for (int m = 0; m < 4; m++)                                                    \
          acc[m][n] = __builtin_amdgcn_mfma_f32_16x16x32_bf16(AL[m], BH[n], acc[m][n], 0,0,0); } }

  for (int kbb = 0; kbb < 32; kbb += 2) {
    { // ---- u0: kb=kbb from buf0 ----
      short8_t BH[4], BL[4];
      #pragma unroll
      for (int n = 0; n < 4; n++) {
        BH[n] = *(const short8_t*)&ldsB[0][((wc*4+n)*2 + 0)*512 + lane*8];
        BL[n] = *(const short8_t*)&ldsB[0][((wc*4+n)*2 + 1)*512 + lane*8];
      }
      if (kbb + 2 < 32) {   // B prefetch early: full-phase latency coverage
        #pragma unroll
        for (int q = 0; q < 4; q++)
          rBa[q] = *(const short8_t*)(wjb + (size_t)(kbb+2)*65536 + sg + q*512);
      }
      DO_MFMA48(AH0, AL0, BH, BL);
      #pragma unroll
      for (int q = 0; q < 4; q++) *(short8_t*)&ldsB[1][sg + q*512] = rBb[q];  // stage kbb+1
      if (kbb + 2 < 32) {   // A prefetch (L2-resident, short gap OK)
        #pragma unroll
        for (int m = 0; m < 4; m++) {
          AH0[m] = *(const short8_t*)(abase[m] + (kbb+2)*64);
          AL0[m] = *(const short8_t*)(abase[m] + (kbb+2)*64 + 32);
        }
      }
      asm volatile("s_waitcnt lgkmcnt(0)" ::: "memory");
      __builtin_amdgcn_s_barrier();
    }
    { // ---- u1: kb=kbb+1 from buf1 ----
      short8_t BH[4], BL[4];
      #pragma unroll
      for (int n = 0; n < 4; n++) {
        BH[n] = *(const short8_t*)&ldsB[1][((wc*4+n)*2 + 0)*512 + lane*8];
        BL[n] = *(const short8_t*)&ldsB[1][((wc*4+n)*2 + 1)*512 + lane*8];
      }
      if (kbb + 3 < 32) {
        #pragma unroll
        for (int q = 0; q < 4; q++)
          rBb[q] = *(const short8_t*)(wjb + (size_t)(kbb+3)*65536 + sg + q*512);
      }
      DO_MFMA48(AH1, AL1, BH, BL);
      if (kbb + 2 < 32) {
        #pragma unroll
        for (int q = 0; q < 4; q++) *(short8_t*)&ldsB[0][sg + q*512] = rBa[q]; // stage kbb+2
      }
      if (kbb + 3 < 32) {
        #pragma unroll
        for (int m = 0; m < 4; m++) {
          AH1[m] = *(const short8_t*)(abase[m] + (kbb+3)*64);
          AL1[m] = *(const short8_t*)(abase[m] + (kbb+3)*64 + 32);
        }
      }
      asm volatile("s_waitcnt lgkmcnt(0)" ::: "memory");
      __builtin_amdgcn_s_barrier();
    }
  }
  #undef DO_MFMA48

  // epilogue: bias (+relu on G1); G1 -> split-blocked Hs, G2 -> fp32 Obuf
  float bv[4];
  #pragma unroll
  for (int n = 0; n < 4; n++)
    bv[n] = bias[e * 1024 + cb*128 + wc*64 + n*16 + l16];
  #pragma unroll
  for (int m = 0; m < 4; m++) {
    #pragma unroll
    for (int n = 0; n < 4; n++) {
      const int col = cb*128 + wc*64 + n*16 + l16;
      #pragma unroll
      for (int jj = 0; jj < 4; jj++) {
        int lr = wr*64 + m*16 + l4*4 + jj;
        if (lr < rows_here) {
          float v = acc[m][n][jj] + bv[n];
          if (IS_G1) {
            v = fmaxf(v, 0.f);
            short hs, ls; splitf(v, hs, ls);
            size_t o = (size_t)(row_start + lr) * 2048 + (col >> 5) * 64 + (col & 31);
            OutS[o] = hs; OutS[o + 32] = ls;
          } else {
            OutF[(size_t)(row_start + lr) * 1024 + col] = v;
          }
        }
      }
    }
  }
}

// ---------------- gather + sum(M) + LayerNorm + scores + MSE (round-5 proven) ----------------
__global__ __launch_bounds__(256) void moe_ln_kernel(
    const float* __restrict__ O,
    const float* __restrict__ tk_gates,
    const int* __restrict__ pair_row,
    const float* __restrict__ ln_w, const float* __restrict__ ln_b,
    const float* __restrict__ W_los, const float* __restrict__ b_los,
    const float* __restrict__ true_y,
    float* __restrict__ out)
{
  __shared__ float fin[D_DIM];
  __shared__ float redx[256];
  __shared__ float redy[256];
  const int b = blockIdx.x, tid = threadIdx.x;
  float4 acc = make_float4(0.f,0.f,0.f,0.f);
  for (int m = 0; m < 16; m++) {
    int n = b*16 + m;
    #pragma unroll
    for (int k = 0; k < TOPK; k++) {
      int p = n*TOPK + k;
      float g = tk_gates[p];
      int row = pair_row[p];
      float4 v = *(const float4*)&O[(size_t)row*D_DIM + tid*4];
      acc.x = fmaf(g, v.x, acc.x);
      acc.y = fmaf(g, v.y, acc.y);
      acc.z = fmaf(g, v.z, acc.z);
      acc.w = fmaf(g, v.w, acc.w);
    }
  }
  float s  = acc.x + acc.y + acc.z + acc.w;
  float s2 = acc.x*acc.x + acc.y*acc.y + acc.z*acc.z + acc.w*acc.w;
  redx[tid] = s; redy[tid] = s2;
  __syncthreads();
  for (int off = 128; off > 0; off >>= 1) {
    if (tid < off) { redx[tid] += redx[tid+off]; redy[tid] += redy[tid+off]; }
    __syncthreads();
  }
  float mean = redx[0] * (1.f/D_DIM);
  float var  = redy[0] * (1.f/D_DIM) - mean*mean;   // ddof=0
  float rstd = rsqrtf(var + 1e-5f);
  int d0 = tid*4;
  fin[d0+0] = (acc.x - mean)*rstd*ln_w[d0+0] + ln_b[d0+0];
  fin[d0+1] = (acc.y - mean)*rstd*ln_w[d0+1] + ln_b[d0+1];
  fin[d0+2] = (acc.z - mean)*rstd*ln_w[d0+2] + ln_b[d0+2];
  fin[d0+3] = (acc.w - mean)*rstd*ln_w[d0+3] + ln_b[d0+3];
  __syncthreads();
  const int wv = tid >> 6, ln = tid & 63;
  for (int o = wv; o < OUT_SZ; o += 4) {
    float p = 0.f;
    for (int d = ln; d < D_DIM; d += 64) p = fmaf(fin[d], W_los[d*OUT_SZ + o], p);
    #pragma unroll
    for (int off = 32; off; off >>= 1) p += __shfl_xor(p, off);
    if (ln == 0) {
      float sc = p + b_los[o];
      out[b*OUT_SZ + o] = sc;
      float d = sc - true_y[b*OUT_SZ + o];
      atomicAdd(&out[641], d * d * (1.f/(B_SZ*OUT_SZ)));
    }
  }
}

// ---------------- launch ----------------
extern "C" void kernel_launch(void* const* d_in, const int* in_sizes, int n_in,
                              void* d_out, int out_size, void* d_ws, size_t ws_size,
                              hipStream_t stream) {
  const float* x      = (const float*)d_in[0];
  const float* wg     = (const float*)d_in[1];
  const float* W1     = (const float*)d_in[2];
  const float* b1     = (const float*)d_in[3];
  const float* W2     = (const float*)d_in[4];
  const float* b2     = (const float*)d_in[5];
  const float* ln_w   = (const float*)d_in[6];
  const float* ln_b   = (const float*)d_in[7];
  const float* W_los  = (const float*)d_in[8];
  const float* b_los  = (const float*)d_in[9];
  const float* true_y = (const float*)d_in[10];
  float* out = (float*)d_out;
  char* ws = (char*)d_ws;

  int*   tk_idx   = (int*)  (ws + WS_TKIDX);
  float* tk_gates = (float*)(ws + WS_TKGATE);
  int*   offsets  = (int*)  (ws + WS_OFFSETS);
  int*   te       = (int*)  (ws + WS_TE);
  int*   trs      = (int*)  (ws + WS_TRS);
  int*   ntile    = (int*)  (ws + WS_NTILE);
  int*   perm_tok = (int*)  (ws + WS_PERMTOK);
  int*   pair_row = (int*)  (ws + WS_PAIRROW);
  short* xs       = (short*)(ws + WS_XS);
  short* Hs       = (short*)(ws + WS_HS);
  float* Obuf     = (float*)(ws + WS_OBUF);
  short* WT       = (short*)(ws + WS_WT);

  // 1: split W1 (blocks 0..4095) + gate/split-x (blocks 4096..4351)
  prep_kernel<<<4352, 256, 0, stream>>>(x, wg, W1, WT, tk_idx, tk_gates, xs);
  // 2: scan + aux loss + scatter + tile table
  scan_scatter_kernel<<<1, 1024, 0, stream>>>(tk_idx, tk_gates, offsets,
                                              perm_tok, pair_row, te, trs, ntile, out);
  // 3: GEMM1 (gathered xs @ W1 -> relu -> split-blocked Hs)
  ffn_gemm<1><<<MAX_TILES*8, 256, 0, stream>>>(
      xs, WT, b1, nullptr, Hs, offsets, te, trs, ntile, perm_tok);
  // 4: split W2 (reuse WT)
  split_w_kernel<<<4096, 256, 0, stream>>>(W2, WT);
  // 5: GEMM2 (Hs @ W2 -> fp32 Obuf)
  ffn_gemm<0><<<MAX_TILES*8, 256, 0, stream>>>(
      Hs, WT, b2, Obuf, nullptr, offsets, te, trs, ntile, perm_tok);
  // 6: gather + LN + scores + MSE
  moe_ln_kernel<<<64, 256, 0, stream>>>(Obuf, tk_gates, pair_row, ln_w, ln_b,
                                        W_los, b_los, true_y, out);
}